// Round 20
// baseline (456.631 us; speedup 1.0000x reference)
//
#include <hip/hip_runtime.h>

#define N_NODES 100000
#define N_EDGES 800000
#define N_GRAPH 512
#define NODE_IN 92
#define NLAYER 3
#define NCHUNK 98           // ceil(100001/1024)
#define CNTPAD 100352       // 98*1024

typedef short bf16x8 __attribute__((ext_vector_type(8)));
typedef float f32x4  __attribute__((ext_vector_type(4)));

#define MFMA16(a, b, c) __builtin_amdgcn_mfma_f32_16x16x32_bf16(a, b, c, 0, 0, 0)

__device__ __forceinline__ short f2bf(float f) {
    union { float f; unsigned u; } v; v.f = f;
    unsigned u = v.u;
    unsigned r = (u + 0x7fffu + ((u >> 16) & 1u)) >> 16;
    return (short)r;
}

// pack two f32 -> one u32 of 2 bf16 (lo = a, hi = b), RNE
__device__ __forceinline__ unsigned pk_bf16(float a, float b) {
    unsigned r;
    asm("v_cvt_pk_bf16_f32 %0, %1, %2" : "=v"(r) : "v"(a), "v"(b));
    return r;
}

// ---------------------------------------------------------------------------
// Node embedding: h = relu(x @ node_w + node_b); writes f32 + bf16 copies.
// Fused: agg zero, gsum/counts zero, dst histogram.
// ---------------------------------------------------------------------------
__global__ __launch_bounds__(256)
void node_embed_kernel(const float* __restrict__ x, const float* __restrict__ nw,
                       const float* __restrict__ nb, float* __restrict__ hout,
                       short* __restrict__ hb, float* __restrict__ agg,
                       const int* __restrict__ dstp, int* __restrict__ cnt,
                       float* __restrict__ gsum_all)
{
    __shared__ float s_x[16 * NODE_IN];
    const int t = threadIdx.x;
    const int j = t & 63, iq = t >> 6;
    const int n0 = blockIdx.x * 16;
    const int gidx = blockIdx.x * 256 + t;

    for (int idx = t; idx < 16 * NODE_IN; idx += 256)
        s_x[idx] = x[(size_t)n0 * NODE_IN + idx];

    float4 z = { 0.f, 0.f, 0.f, 0.f };
    *(float4*)(agg + (size_t)n0 * 64 + t * 4) = z;
    if (gidx < N_GRAPH * 65) gsum_all[gidx] = 0.f;          // gsum + counts
    if (gidx < N_EDGES) atomicAdd(&cnt[dstp[gidx] + 1], 1); // histogram
    __syncthreads();

    float acc[4];
    const float bj = nb[j];
#pragma unroll
    for (int q = 0; q < 4; ++q) acc[q] = bj;

#pragma unroll 4
    for (int k = 0; k < NODE_IN; ++k) {
        float wv = nw[k * 64 + j];
#pragma unroll
        for (int q = 0; q < 4; ++q)
            acc[q] += s_x[(iq + q * 4) * NODE_IN + k] * wv;
    }
#pragma unroll
    for (int q = 0; q < 4; ++q) {
        int n = n0 + iq + q * 4;
        float v = fmaxf(acc[q], 0.f);
        hout[(size_t)n * 64 + j] = v;
        hb[(size_t)n * 64 + j] = f2bf(v);
    }
}

// ---------------------------------------------------------------------------
// Counting sort of edges by dst: scan + scatter-permute (hist done above)
// ---------------------------------------------------------------------------
__global__ __launch_bounds__(256)
void scan_chunk_sums(const int* __restrict__ cnt, int* __restrict__ bsums)
{
    __shared__ int s[256];
    const int b = blockIdx.x, t = threadIdx.x;
    int base = b * 1024 + t * 4, v = 0;
#pragma unroll
    for (int k = 0; k < 4; ++k) {
        int idx = base + k;
        if (idx < N_NODES + 1) v += cnt[idx];
    }
    s[t] = v; __syncthreads();
    for (int off = 128; off > 0; off >>= 1) {
        if (t < off) s[t] += s[t + off];
        __syncthreads();
    }
    if (t == 0) bsums[b] = s[0];
}

__global__ void scan_bsums(int* __restrict__ bsums)
{
    if (threadIdx.x == 0 && blockIdx.x == 0) {
        int run = 0;
        for (int i = 0; i < NCHUNK; ++i) { int v = bsums[i]; bsums[i] = run; run += v; }
    }
}

__global__ __launch_bounds__(1024)
void scan_apply(int* __restrict__ cnt, const int* __restrict__ bsums)
{
    __shared__ int s[1024];
    const int b = blockIdx.x, t = threadIdx.x;
    const int idx = b * 1024 + t;
    int v = (idx < N_NODES + 1) ? cnt[idx] : 0;
    s[t] = v; __syncthreads();
    for (int off = 1; off < 1024; off <<= 1) {
        int x = (t >= off) ? s[t - off] : 0;
        __syncthreads();
        s[t] += x;
        __syncthreads();
    }
    if (idx < N_NODES + 1) cnt[idx] = s[t] + bsums[b];
}

__global__ __launch_bounds__(256)
void scatter_kernel(const int* __restrict__ src, const int* __restrict__ dst,
                    const float* __restrict__ eattr,
                    const int* __restrict__ off, int* __restrict__ pos,
                    int* __restrict__ src_p, int* __restrict__ dst_p,
                    short* __restrict__ ea_p)
{
    int e = blockIdx.x * 256 + threadIdx.x;
    if (e >= N_EDGES) return;
    int d = dst[e];
    int p = off[d] + atomicAdd(&pos[d], 1);
    src_p[p] = src[e];
    dst_p[p] = d;
    const float4* ap = (const float4*)(eattr + (size_t)e * 16);
    float4 v0 = ap[0], v1 = ap[1], v2 = ap[2], v3 = ap[3];
    union { short s[16]; int4 v[2]; } u;
    u.s[0] = f2bf(v0.x); u.s[1] = f2bf(v0.y); u.s[2]  = f2bf(v0.z); u.s[3]  = f2bf(v0.w);
    u.s[4] = f2bf(v1.x); u.s[5] = f2bf(v1.y); u.s[6]  = f2bf(v1.z); u.s[7]  = f2bf(v1.w);
    u.s[8] = f2bf(v2.x); u.s[9] = f2bf(v2.y); u.s[10] = f2bf(v2.z); u.s[11] = f2bf(v2.w);
    u.s[12]= f2bf(v3.x); u.s[13]= f2bf(v3.y); u.s[14] = f2bf(v3.z); u.s[15] = f2bf(v3.w);
    *(int4*)(ea_p + (size_t)p * 16)     = u.v[0];
    *(int4*)(ea_p + (size_t)p * 16 + 8) = u.v[1];
}

// ---------------------------------------------------------------------------
// Edge MLP, mega-block + 32-edge tiles (round-18 structure: readlane dst
// broadcast, scalar index prefetch, wave-private tiles). Round 20: T5
// s_setprio(1) around the MFMA clusters — 12 independent waves/CU at
// different phases give the scheduler role diversity to arbitrate.
// ---------------------------------------------------------------------------
__global__ __launch_bounds__(768, 3)
void edge_mlp_mfma(const short* __restrict__ hb,
                   const int* __restrict__ src_p,
                   const int* __restrict__ dst_p,
                   const short* __restrict__ ea_p,
                   const float* __restrict__ we, const float* __restrict__ be,
                   const float* __restrict__ w1, const float* __restrict__ b1,
                   const float* __restrict__ w2, const float* __restrict__ b2,
                   float* __restrict__ agg)
{
    __shared__ __align__(16) short s_w1t[128 * 128];  // 32K  W1^T [j][k] swizzled
    __shared__ __align__(16) short s_w2t[64 * 128];   // 16K  W2^T [j][k] swizzled
    __shared__ __align__(16) short s_wet[64 * 16];    // 2K   we^T [j][k]
    __shared__ __align__(16) short s_mi[12][32 * 128];// 96K  per-wave 32-edge tile

    const int t = threadIdx.x;

    // ---- one-time weight staging into LDS (coalesced, all waves) ----
    for (int c = t; c < 128 * 16; c += 768) {          // W1^T
        int k = c & 127, j8 = c >> 7;
        const float4* wp = (const float4*)(w1 + (size_t)k * 128 + j8 * 8);
        float4 x0 = wp[0], x1 = wp[1];
        short vals[8] = { f2bf(x0.x), f2bf(x0.y), f2bf(x0.z), f2bf(x0.w),
                          f2bf(x1.x), f2bf(x1.y), f2bf(x1.z), f2bf(x1.w) };
        int slot = k >> 3, kin = k & 7;
#pragma unroll
        for (int u2 = 0; u2 < 8; ++u2) {
            int row = j8 * 8 + u2;
            s_w1t[row * 128 + ((slot ^ (row & 7)) << 3) + kin] = vals[u2];
        }
    }
    for (int c = t; c < 128 * 8; c += 768) {           // W2^T
        int k = c & 127, j8 = c >> 7;
        const float4* wp = (const float4*)(w2 + (size_t)k * 64 + j8 * 8);
        float4 x0 = wp[0], x1 = wp[1];
        short vals[8] = { f2bf(x0.x), f2bf(x0.y), f2bf(x0.z), f2bf(x0.w),
                          f2bf(x1.x), f2bf(x1.y), f2bf(x1.z), f2bf(x1.w) };
        int slot = k >> 3, kin = k & 7;
#pragma unroll
        for (int u2 = 0; u2 < 8; ++u2) {
            int row = j8 * 8 + u2;
            s_w2t[row * 128 + ((slot ^ (row & 7)) << 3) + kin] = vals[u2];
        }
    }
    for (int idx = t; idx < 16 * 64; idx += 768) {     // we^T [j][k]
        int k = idx & 15, jj = idx >> 4;
        s_wet[jj * 16 + k] = f2bf(we[k * 64 + jj]);
    }
    __syncthreads();

    const int u  = t >> 6;        // wave id 0..11 (independent worker)
    const int l  = t & 63;        // lane
    const int rl = l & 15;
    const int hi = l >> 4;

    const int er   = l >> 1;      // staging edge row 0..31
    const int part = l & 1;
    const int swz  = rl & 7;

    short* mi = &s_mi[u][0];
    const int NCH = N_EDGES / 32;                 // 25000 32-edge chunks

    int chunk = blockIdx.x * 12 + u;
    int sn_next = 0, dst_next = 0;
    if (chunk < NCH) {
        sn_next = src_p[chunk * 32 + er];
        if (l < 32) dst_next = dst_p[chunk * 32 + l];
    }

    while (chunk < NCH) {
        const int e0 = chunk * 32;
        const int sn   = sn_next;      // prefetched this-chunk src index
        const int dstv = dst_next;     // prefetched this-chunk dst (lanes 0..31)

        const int nx = chunk + 3072;
        if (nx < NCH) {                 // issue next-chunk index loads early
            sn_next = src_p[nx * 32 + er];
            if (l < 32) dst_next = dst_p[nx * 32 + l];
        }

        // ---- stage (wave-private): gathered h, raw ea -> slots 14/15 ----
        {
            const int4* hp = (const int4*)(hb + (size_t)sn * 64 + part * 32);
#pragma unroll
            for (int c = 0; c < 4; ++c) {
                int4 v = hp[c];
                int slot = part * 4 + c;
                *(int4*)&mi[er * 128 + ((slot ^ (er & 7)) << 3)] = v;
            }
            const int4* ap = (const int4*)(ea_p + (size_t)(e0 + er) * 16 + part * 8);
            *(int4*)&mi[er * 128 + (((14 + part) ^ (er & 7)) << 3)] = ap[0];
        }

        // ---- edge embedding (swapped): ea[e][j] -> m_in cols 64..127 ----
        {
            bf16x8 eb0 = { 0, 0, 0, 0, 0, 0, 0, 0 };
            bf16x8 eb1 = { 0, 0, 0, 0, 0, 0, 0, 0 };
            if (hi < 2) {
                eb0 = *(const bf16x8*)&mi[rl * 128 + (((14 + hi) ^ swz) << 3)];
                eb1 = *(const bf16x8*)&mi[(16 + rl) * 128 + (((14 + hi) ^ swz) << 3)];
            }
            __builtin_amdgcn_s_setprio(1);
#pragma unroll
            for (int jb = 0; jb < 4; ++jb) {
                bf16x8 afr = { 0, 0, 0, 0, 0, 0, 0, 0 };
                if (hi < 2) afr = *(const bf16x8*)&s_wet[(jb * 16 + rl) * 16 + hi * 8];
                const float4 bj4 = *(const float4*)(be + jb * 16 + 4 * hi);
                f32x4 c0 = { bj4.x, bj4.y, bj4.z, bj4.w };
                f32x4 c1 = c0;
                c0 = MFMA16(afr, eb0, c0);
                c1 = MFMA16(afr, eb1, c1);
                const int col = 64 + jb * 16 + 4 * hi;
                const int coff = (((col >> 3) ^ swz) << 3) + (col & 7);
                int2 pk;
                pk.x = (int)pk_bf16(fmaxf(c0[0], 0.f), fmaxf(c0[1], 0.f));
                pk.y = (int)pk_bf16(fmaxf(c0[2], 0.f), fmaxf(c0[3], 0.f));
                *(int2*)&mi[rl * 128 + coff] = pk;
                pk.x = (int)pk_bf16(fmaxf(c1[0], 0.f), fmaxf(c1[1], 0.f));
                pk.y = (int)pk_bf16(fmaxf(c1[2], 0.f), fmaxf(c1[3], 0.f));
                *(int2*)&mi[(16 + rl) * 128 + coff] = pk;
            }
            __builtin_amdgcn_s_setprio(0);
        }

        // ---- GEMM1 (swapped): hidden[e][j] = relu(m_in @ W1 + b1) ----
        {
            bf16x8 bf0[4], bf1[4];
#pragma unroll
            for (int s = 0; s < 4; ++s) {
                const int soff = (((4 * s + hi) ^ swz) << 3);
                bf0[s] = *(const bf16x8*)&mi[rl * 128 + soff];
                bf1[s] = *(const bf16x8*)&mi[(16 + rl) * 128 + soff];
            }
            __builtin_amdgcn_s_setprio(1);
#pragma unroll
            for (int jb = 0; jb < 8; ++jb) {
                const float4 bj4 = *(const float4*)(b1 + jb * 16 + 4 * hi);
                f32x4 c0 = { bj4.x, bj4.y, bj4.z, bj4.w };
                f32x4 c1 = c0;
#pragma unroll
                for (int s = 0; s < 4; ++s) {
                    bf16x8 afr = *(const bf16x8*)&s_w1t[(jb * 16 + rl) * 128 + (((4 * s + hi) ^ swz) << 3)];
                    c0 = MFMA16(afr, bf0[s], c0);
                    c1 = MFMA16(afr, bf1[s], c1);
                }
                const int col = jb * 16 + 4 * hi;
                const int coff = (((col >> 3) ^ swz) << 3) + (col & 7);
                int2 pk;
                pk.x = (int)pk_bf16(fmaxf(c0[0], 0.f), fmaxf(c0[1], 0.f));
                pk.y = (int)pk_bf16(fmaxf(c0[2], 0.f), fmaxf(c0[3], 0.f));
                *(int2*)&mi[rl * 128 + coff] = pk;
                pk.x = (int)pk_bf16(fmaxf(c1[0], 0.f), fmaxf(c1[1], 0.f));
                pk.y = (int)pk_bf16(fmaxf(c1[2], 0.f), fmaxf(c1[3], 0.f));
                *(int2*)&mi[(16 + rl) * 128 + coff] = pk;
            }
            __builtin_amdgcn_s_setprio(0);
        }

        // ---- GEMM2 (swapped): m[e][j] = hidden @ W2 + b2 -> f32 b128 w ----
        {
            bf16x8 hf0[4], hf1[4];
#pragma unroll
            for (int s = 0; s < 4; ++s) {
                const int soff = (((4 * s + hi) ^ swz) << 3);
                hf0[s] = *(const bf16x8*)&mi[rl * 128 + soff];
                hf1[s] = *(const bf16x8*)&mi[(16 + rl) * 128 + soff];
            }
            float* s_red = (float*)mi;                 // 32x64 f32, wave region
            __builtin_amdgcn_s_setprio(1);
#pragma unroll
            for (int n = 0; n < 4; ++n) {
                const float4 bj4 = *(const float4*)(b2 + n * 16 + 4 * hi);
                f32x4 c0 = { bj4.x, bj4.y, bj4.z, bj4.w };
                f32x4 c1 = c0;
#pragma unroll
                for (int s = 0; s < 4; ++s) {
                    bf16x8 afr = *(const bf16x8*)&s_w2t[(n * 16 + rl) * 128 + (((4 * s + hi) ^ swz) << 3)];
                    c0 = MFMA16(afr, hf0[s], c0);
                    c1 = MFMA16(afr, hf1[s], c1);
                }
                const int pslot = (n * 4 + hi) ^ (rl & 3);   // bank-spread slot
                *(f32x4*)&s_red[rl * 64 + pslot * 4] = c0;
                *(f32x4*)&s_red[(16 + rl) * 64 + pslot * 4] = c1;
            }
            __builtin_amdgcn_s_setprio(0);
        }

        // ---- segmented reduce over the wave's 32 sorted edges ----
        {
            const float* s_red = (const float*)mi;
            const int lq = l >> 2, lo2 = l & 3;
            float acc = 0.f;
            int cur = __builtin_amdgcn_readlane(dstv, 0);
            bool first = true;
#pragma unroll
            for (int r = 0; r < 32; ++r) {
                int d = __builtin_amdgcn_readlane(dstv, r);
                if (d != cur) {
                    float* ap2 = agg + (size_t)cur * 64 + l;
                    if (first) atomicAdd(ap2, acc);
                    else       *ap2 = acc;           // interior run: exclusive
                    first = false; acc = 0.f; cur = d;
                }
                acc += s_red[r * 64 + ((lq ^ (r & 3)) << 2) + lo2];
            }
            atomicAdd(agg + (size_t)cur * 64 + l, acc);  // touches window end
        }

        chunk = nx;
    }
}

// ---------------------------------------------------------------------------
// Self update (in place): h = relu(agg + h @ self_w + self_b).
// zero_agg: zero agg after reading. last: skip all global h/hb writes and do
// fused graph pooling via block-level LDS pre-reduction (low contention).
// ---------------------------------------------------------------------------
__global__ __launch_bounds__(256)
void self_update_kernel(float* h, short* hb, float* agg,
                        const float* __restrict__ sw, const float* __restrict__ sb,
                        int zero_agg, int last,
                        const int* __restrict__ batch,
                        float* __restrict__ gsum, float* __restrict__ counts)
{
    __shared__ float s_h[16 * 64];
    __shared__ int s_b[16];
    const int t = threadIdx.x;
    const int j = t & 63, iq = t >> 6;
    const int n0 = blockIdx.x * 16;

    for (int idx = t; idx < 16 * 64; idx += 256)
        s_h[idx] = h[(size_t)n0 * 64 + idx];
    if (last && t < 16) s_b[t] = batch[n0 + t];
    __syncthreads();

    float acc[4];
    const float bj = sb[j];
#pragma unroll
    for (int q = 0; q < 4; ++q) acc[q] = bj;

#pragma unroll 4
    for (int k = 0; k < 64; ++k) {
        float wv = sw[k * 64 + j];
#pragma unroll
        for (int q = 0; q < 4; ++q)
            acc[q] += s_h[(iq + q * 4) * 64 + k] * wv;
    }

    if (!last) {
#pragma unroll
        for (int q = 0; q < 4; ++q) {
            int n = n0 + iq + q * 4;
            float v = fmaxf(acc[q] + agg[(size_t)n * 64 + j], 0.f);
            h[(size_t)n * 64 + j] = v;
            hb[(size_t)n * 64 + j] = f2bf(v);
            if (zero_agg) agg[(size_t)n * 64 + j] = 0.f;
        }
    } else {
        // compute v and park it in the (now-dead) s_h tile
        float vq[4];
#pragma unroll
        for (int q = 0; q < 4; ++q) {
            int n = n0 + iq + q * 4;
            vq[q] = fmaxf(acc[q] + agg[(size_t)n * 64 + j], 0.f);
        }
        __syncthreads();             // all s_h reads complete
#pragma unroll
        for (int q = 0; q < 4; ++q)
            s_h[(iq + q * 4) * 64 + j] = vq[q];
        __syncthreads();

        // block-level pooling: 64 threads run-length column t over 16 nodes
        if (t < 64) {
            int cur = s_b[0];
            float sum = 0.f, cnt = 0.f;
#pragma unroll
            for (int nn = 0; nn < 16; ++nn) {
                int b = s_b[nn];
                if (b != cur) {
                    atomicAdd(gsum + (size_t)cur * 64 + t, sum);
                    if (t == 0) atomicAdd(counts + cur, cnt);
                    sum = 0.f; cnt = 0.f; cur = b;
                }
                sum += s_h[nn * 64 + t];
                cnt += 1.f;
            }
            atomicAdd(gsum + (size_t)cur * 64 + t, sum);
            if (t == 0) atomicAdd(counts + cur, cnt);
        }
    }
}

// ---------------------------------------------------------------------------
// Readout
// ---------------------------------------------------------------------------
__global__ __launch_bounds__(64)
void readout_kernel(const float* __restrict__ gsum, const float* __restrict__ counts,
                    const float* __restrict__ w1, const float* __restrict__ b1,
                    const float* __restrict__ w2, const float* __restrict__ b2,
                    float* __restrict__ out)
{
    __shared__ float s_g[128];
    const int g = blockIdx.x, t = threadIdx.x;
    float sv = gsum[(size_t)g * 64 + t];
    float c = fmaxf(counts[g], 1.f);
    s_g[t] = sv;
    s_g[64 + t] = sv / c;
    __syncthreads();

    float acc = b1[t];
#pragma unroll 4
    for (int k = 0; k < 128; ++k)
        acc += s_g[k] * w1[k * 64 + t];
    acc = fmaxf(acc, 0.f);

    float p = acc * w2[t];
#pragma unroll
    for (int m = 1; m < 64; m <<= 1)
        p += __shfl_xor(p, m, 64);
    if (t == 0) out[g] = p + b2[0];
}

// ---------------------------------------------------------------------------
extern "C" void kernel_launch(void* const* d_in, const int* in_sizes, int n_in,
                              void* d_out, int out_size, void* d_ws, size_t ws_size,
                              hipStream_t stream)
{
    const float* x      = (const float*)d_in[0];
    const int*   eidx   = (const int*)d_in[1];
    const float* eattr  = (const float*)d_in[2];
    const int*   batch  = (const int*)d_in[3];
    const float* node_w = (const float*)d_in[4];
    const float* node_b = (const float*)d_in[5];
    const float* edge_w = (const float*)d_in[6];
    const float* edge_b = (const float*)d_in[7];
    const float* msg_w1 = (const float*)d_in[8];
    const float* msg_b1 = (const float*)d_in[9];
    const float* msg_w2 = (const float*)d_in[10];
    const float* msg_b2 = (const float*)d_in[11];
    const float* self_w = (const float*)d_in[12];
    const float* self_b = (const float*)d_in[13];
    const float* ro_w1  = (const float*)d_in[14];
    const float* ro_b1  = (const float*)d_in[15];
    const float* ro_w2  = (const float*)d_in[16];
    const float* ro_b2  = (const float*)d_in[17];
    float* out = (float*)d_out;

    char* wsp = (char*)d_ws;
    float* h      = (float*)wsp;                         wsp += (size_t)N_NODES * 64 * 4;
    float* agg    = (float*)wsp;                         wsp += (size_t)N_NODES * 64 * 4;
    short* hb     = (short*)wsp;                         wsp += (size_t)N_NODES * 64 * 2;
    int*   src_p  = (int*)wsp;                           wsp += (size_t)N_EDGES * 4;
    int*   dst_p  = (int*)wsp;                           wsp += (size_t)N_EDGES * 4;
    short* ea_p   = (short*)wsp;                         wsp += (size_t)N_EDGES * 16 * 2;
    float* gsum   = (float*)wsp;                         wsp += (size_t)N_GRAPH * 64 * 4;
    float* counts = (float*)wsp;                         wsp += (size_t)N_GRAPH * 4;
    int*   cnt    = (int*)wsp;                           wsp += (size_t)CNTPAD * 4;
    int*   pos    = (int*)wsp;                           wsp += (size_t)CNTPAD * 4;
    int*   bsums  = (int*)wsp;                           wsp += (size_t)(NCHUNK + 32) * 4;

    const int* srcp = eidx;
    const int* dstp = eidx + N_EDGES;

    // cnt/pos must be zero before the fused histogram in node_embed
    hipMemsetAsync(cnt, 0, (size_t)(2 * CNTPAD + 128) * sizeof(int), stream);

    // node embedding + agg zero + gsum/counts zero + dst histogram
    node_embed_kernel<<<N_NODES / 16, 256, 0, stream>>>(
        x, node_w, node_b, h, hb, agg, dstp, cnt, gsum);

    // ---- one-time dst-sort of edges ----
    scan_chunk_sums<<<NCHUNK, 256, 0, stream>>>(cnt, bsums);
    scan_bsums<<<1, 64, 0, stream>>>(bsums);
    scan_apply<<<NCHUNK, 1024, 0, stream>>>(cnt, bsums);
    scatter_kernel<<<(N_EDGES + 255) / 256, 256, 0, stream>>>(
        srcp, dstp, eattr, cnt, pos, src_p, dst_p, ea_p);

    for (int l = 0; l < NLAYER; ++l) {
        edge_mlp_mfma<<<256, 768, 0, stream>>>(
            hb, src_p, dst_p, ea_p, edge_w, edge_b,
            msg_w1 + (size_t)l * 128 * 128, msg_b1 + (size_t)l * 128,
            msg_w2 + (size_t)l * 128 * 64,  msg_b2 + (size_t)l * 64,
            agg);
        self_update_kernel<<<N_NODES / 16, 256, 0, stream>>>(
            h, hb, agg, self_w + (size_t)l * 64 * 64, self_b + (size_t)l * 64,
            (l < NLAYER - 1) ? 1 : 0, (l == NLAYER - 1) ? 1 : 0,
            batch, gsum, counts);
    }

    readout_kernel<<<N_GRAPH, 64, 0, stream>>>(gsum, counts, ro_w1, ro_b1, ro_w2, ro_b2, out);
}

// Round 21
// 445.192 us; speedup vs baseline: 1.0257x; 1.0257x over previous
//
#include <hip/hip_runtime.h>

#define N_NODES 100000
#define N_EDGES 800000
#define N_GRAPH 512
#define NODE_IN 92
#define NLAYER 3
#define NCHUNK 98           // ceil(100001/1024)
#define CNTPAD 100352       // 98*1024

typedef short bf16x8 __attribute__((ext_vector_type(8)));
typedef float f32x4  __attribute__((ext_vector_type(4)));

#define MFMA16(a, b, c) __builtin_amdgcn_mfma_f32_16x16x32_bf16(a, b, c, 0, 0, 0)

__device__ __forceinline__ short f2bf(float f) {
    union { float f; unsigned u; } v; v.f = f;
    unsigned u = v.u;
    unsigned r = (u + 0x7fffu + ((u >> 16) & 1u)) >> 16;
    return (short)r;
}

// pack two f32 -> one u32 of 2 bf16 (lo = a, hi = b), RNE
__device__ __forceinline__ unsigned pk_bf16(float a, float b) {
    unsigned r;
    asm("v_cvt_pk_bf16_f32 %0, %1, %2" : "=v"(r) : "v"(a), "v"(b));
    return r;
}

// ---------------------------------------------------------------------------
// Node embedding: h = relu(x @ node_w + node_b); writes f32 + bf16 copies.
// Fused: agg zero, gsum/counts zero, dst histogram.
// ---------------------------------------------------------------------------
__global__ __launch_bounds__(256)
void node_embed_kernel(const float* __restrict__ x, const float* __restrict__ nw,
                       const float* __restrict__ nb, float* __restrict__ hout,
                       short* __restrict__ hb, float* __restrict__ agg,
                       const int* __restrict__ dstp, int* __restrict__ cnt,
                       float* __restrict__ gsum_all)
{
    __shared__ float s_x[16 * NODE_IN];
    const int t = threadIdx.x;
    const int j = t & 63, iq = t >> 6;
    const int n0 = blockIdx.x * 16;
    const int gidx = blockIdx.x * 256 + t;

    for (int idx = t; idx < 16 * NODE_IN; idx += 256)
        s_x[idx] = x[(size_t)n0 * NODE_IN + idx];

    float4 z = { 0.f, 0.f, 0.f, 0.f };
    *(float4*)(agg + (size_t)n0 * 64 + t * 4) = z;
    if (gidx < N_GRAPH * 65) gsum_all[gidx] = 0.f;          // gsum + counts
    if (gidx < N_EDGES) atomicAdd(&cnt[dstp[gidx] + 1], 1); // histogram
    __syncthreads();

    float acc[4];
    const float bj = nb[j];
#pragma unroll
    for (int q = 0; q < 4; ++q) acc[q] = bj;

#pragma unroll 4
    for (int k = 0; k < NODE_IN; ++k) {
        float wv = nw[k * 64 + j];
#pragma unroll
        for (int q = 0; q < 4; ++q)
            acc[q] += s_x[(iq + q * 4) * NODE_IN + k] * wv;
    }
#pragma unroll
    for (int q = 0; q < 4; ++q) {
        int n = n0 + iq + q * 4;
        float v = fmaxf(acc[q], 0.f);
        hout[(size_t)n * 64 + j] = v;
        hb[(size_t)n * 64 + j] = f2bf(v);
    }
}

// ---------------------------------------------------------------------------
// Counting sort of edges by dst: scan + scatter-permute (hist done above)
// ---------------------------------------------------------------------------
__global__ __launch_bounds__(256)
void scan_chunk_sums(const int* __restrict__ cnt, int* __restrict__ bsums)
{
    __shared__ int s[256];
    const int b = blockIdx.x, t = threadIdx.x;
    int base = b * 1024 + t * 4, v = 0;
#pragma unroll
    for (int k = 0; k < 4; ++k) {
        int idx = base + k;
        if (idx < N_NODES + 1) v += cnt[idx];
    }
    s[t] = v; __syncthreads();
    for (int off = 128; off > 0; off >>= 1) {
        if (t < off) s[t] += s[t + off];
        __syncthreads();
    }
    if (t == 0) bsums[b] = s[0];
}

__global__ void scan_bsums(int* __restrict__ bsums)
{
    if (threadIdx.x == 0 && blockIdx.x == 0) {
        int run = 0;
        for (int i = 0; i < NCHUNK; ++i) { int v = bsums[i]; bsums[i] = run; run += v; }
    }
}

__global__ __launch_bounds__(1024)
void scan_apply(int* __restrict__ cnt, const int* __restrict__ bsums)
{
    __shared__ int s[1024];
    const int b = blockIdx.x, t = threadIdx.x;
    const int idx = b * 1024 + t;
    int v = (idx < N_NODES + 1) ? cnt[idx] : 0;
    s[t] = v; __syncthreads();
    for (int off = 1; off < 1024; off <<= 1) {
        int x = (t >= off) ? s[t - off] : 0;
        __syncthreads();
        s[t] += x;
        __syncthreads();
    }
    if (idx < N_NODES + 1) cnt[idx] = s[t] + bsums[b];
}

__global__ __launch_bounds__(256)
void scatter_kernel(const int* __restrict__ src, const int* __restrict__ dst,
                    const float* __restrict__ eattr,
                    const int* __restrict__ off, int* __restrict__ pos,
                    int* __restrict__ src_p, int* __restrict__ dst_p,
                    short* __restrict__ ea_p)
{
    int e = blockIdx.x * 256 + threadIdx.x;
    if (e >= N_EDGES) return;
    int d = dst[e];
    int p = off[d] + atomicAdd(&pos[d], 1);
    src_p[p] = src[e];
    dst_p[p] = d;
    const float4* ap = (const float4*)(eattr + (size_t)e * 16);
    float4 v0 = ap[0], v1 = ap[1], v2 = ap[2], v3 = ap[3];
    union { short s[16]; int4 v[2]; } u;
    u.s[0] = f2bf(v0.x); u.s[1] = f2bf(v0.y); u.s[2]  = f2bf(v0.z); u.s[3]  = f2bf(v0.w);
    u.s[4] = f2bf(v1.x); u.s[5] = f2bf(v1.y); u.s[6]  = f2bf(v1.z); u.s[7]  = f2bf(v1.w);
    u.s[8] = f2bf(v2.x); u.s[9] = f2bf(v2.y); u.s[10] = f2bf(v2.z); u.s[11] = f2bf(v2.w);
    u.s[12]= f2bf(v3.x); u.s[13]= f2bf(v3.y); u.s[14] = f2bf(v3.z); u.s[15] = f2bf(v3.w);
    *(int4*)(ea_p + (size_t)p * 16)     = u.v[0];
    *(int4*)(ea_p + (size_t)p * 16 + 8) = u.v[1];
}

// ---------------------------------------------------------------------------
// Edge MLP, mega-block + 32-edge tiles (round-18/19 version, best measured:
// readlane dst broadcast, scalar index prefetch, wave-private tiles).
// ---------------------------------------------------------------------------
__global__ __launch_bounds__(768, 3)
void edge_mlp_mfma(const short* __restrict__ hb,
                   const int* __restrict__ src_p,
                   const int* __restrict__ dst_p,
                   const short* __restrict__ ea_p,
                   const float* __restrict__ we, const float* __restrict__ be,
                   const float* __restrict__ w1, const float* __restrict__ b1,
                   const float* __restrict__ w2, const float* __restrict__ b2,
                   float* __restrict__ agg)
{
    __shared__ __align__(16) short s_w1t[128 * 128];  // 32K  W1^T [j][k] swizzled
    __shared__ __align__(16) short s_w2t[64 * 128];   // 16K  W2^T [j][k] swizzled
    __shared__ __align__(16) short s_wet[64 * 16];    // 2K   we^T [j][k]
    __shared__ __align__(16) short s_mi[12][32 * 128];// 96K  per-wave 32-edge tile

    const int t = threadIdx.x;

    // ---- one-time weight staging into LDS (coalesced, all waves) ----
    for (int c = t; c < 128 * 16; c += 768) {          // W1^T
        int k = c & 127, j8 = c >> 7;
        const float4* wp = (const float4*)(w1 + (size_t)k * 128 + j8 * 8);
        float4 x0 = wp[0], x1 = wp[1];
        short vals[8] = { f2bf(x0.x), f2bf(x0.y), f2bf(x0.z), f2bf(x0.w),
                          f2bf(x1.x), f2bf(x1.y), f2bf(x1.z), f2bf(x1.w) };
        int slot = k >> 3, kin = k & 7;
#pragma unroll
        for (int u2 = 0; u2 < 8; ++u2) {
            int row = j8 * 8 + u2;
            s_w1t[row * 128 + ((slot ^ (row & 7)) << 3) + kin] = vals[u2];
        }
    }
    for (int c = t; c < 128 * 8; c += 768) {           // W2^T
        int k = c & 127, j8 = c >> 7;
        const float4* wp = (const float4*)(w2 + (size_t)k * 64 + j8 * 8);
        float4 x0 = wp[0], x1 = wp[1];
        short vals[8] = { f2bf(x0.x), f2bf(x0.y), f2bf(x0.z), f2bf(x0.w),
                          f2bf(x1.x), f2bf(x1.y), f2bf(x1.z), f2bf(x1.w) };
        int slot = k >> 3, kin = k & 7;
#pragma unroll
        for (int u2 = 0; u2 < 8; ++u2) {
            int row = j8 * 8 + u2;
            s_w2t[row * 128 + ((slot ^ (row & 7)) << 3) + kin] = vals[u2];
        }
    }
    for (int idx = t; idx < 16 * 64; idx += 768) {     // we^T [j][k]
        int k = idx & 15, jj = idx >> 4;
        s_wet[jj * 16 + k] = f2bf(we[k * 64 + jj]);
    }
    __syncthreads();

    const int u  = t >> 6;        // wave id 0..11 (independent worker)
    const int l  = t & 63;        // lane
    const int rl = l & 15;
    const int hi = l >> 4;

    const int er   = l >> 1;      // staging edge row 0..31
    const int part = l & 1;
    const int swz  = rl & 7;

    short* mi = &s_mi[u][0];
    const int NCH = N_EDGES / 32;                 // 25000 32-edge chunks

    int chunk = blockIdx.x * 12 + u;
    int sn_next = 0, dst_next = 0;
    if (chunk < NCH) {
        sn_next = src_p[chunk * 32 + er];
        if (l < 32) dst_next = dst_p[chunk * 32 + l];
    }

    while (chunk < NCH) {
        const int e0 = chunk * 32;
        const int sn   = sn_next;      // prefetched this-chunk src index
        const int dstv = dst_next;     // prefetched this-chunk dst (lanes 0..31)

        const int nx = chunk + 3072;
        if (nx < NCH) {                 // issue next-chunk index loads early
            sn_next = src_p[nx * 32 + er];
            if (l < 32) dst_next = dst_p[nx * 32 + l];
        }

        // ---- stage (wave-private): gathered h, raw ea -> slots 14/15 ----
        {
            const int4* hp = (const int4*)(hb + (size_t)sn * 64 + part * 32);
#pragma unroll
            for (int c = 0; c < 4; ++c) {
                int4 v = hp[c];
                int slot = part * 4 + c;
                *(int4*)&mi[er * 128 + ((slot ^ (er & 7)) << 3)] = v;
            }
            const int4* ap = (const int4*)(ea_p + (size_t)(e0 + er) * 16 + part * 8);
            *(int4*)&mi[er * 128 + (((14 + part) ^ (er & 7)) << 3)] = ap[0];
        }

        // ---- edge embedding (swapped): ea[e][j] -> m_in cols 64..127 ----
        {
            bf16x8 eb0 = { 0, 0, 0, 0, 0, 0, 0, 0 };
            bf16x8 eb1 = { 0, 0, 0, 0, 0, 0, 0, 0 };
            if (hi < 2) {
                eb0 = *(const bf16x8*)&mi[rl * 128 + (((14 + hi) ^ swz) << 3)];
                eb1 = *(const bf16x8*)&mi[(16 + rl) * 128 + (((14 + hi) ^ swz) << 3)];
            }
#pragma unroll
            for (int jb = 0; jb < 4; ++jb) {
                bf16x8 afr = { 0, 0, 0, 0, 0, 0, 0, 0 };
                if (hi < 2) afr = *(const bf16x8*)&s_wet[(jb * 16 + rl) * 16 + hi * 8];
                const float4 bj4 = *(const float4*)(be + jb * 16 + 4 * hi);
                f32x4 c0 = { bj4.x, bj4.y, bj4.z, bj4.w };
                f32x4 c1 = c0;
                c0 = MFMA16(afr, eb0, c0);
                c1 = MFMA16(afr, eb1, c1);
                const int col = 64 + jb * 16 + 4 * hi;
                const int coff = (((col >> 3) ^ swz) << 3) + (col & 7);
                int2 pk;
                pk.x = (int)pk_bf16(fmaxf(c0[0], 0.f), fmaxf(c0[1], 0.f));
                pk.y = (int)pk_bf16(fmaxf(c0[2], 0.f), fmaxf(c0[3], 0.f));
                *(int2*)&mi[rl * 128 + coff] = pk;
                pk.x = (int)pk_bf16(fmaxf(c1[0], 0.f), fmaxf(c1[1], 0.f));
                pk.y = (int)pk_bf16(fmaxf(c1[2], 0.f), fmaxf(c1[3], 0.f));
                *(int2*)&mi[(16 + rl) * 128 + coff] = pk;
            }
        }

        // ---- GEMM1 (swapped): hidden[e][j] = relu(m_in @ W1 + b1) ----
        {
            bf16x8 bf0[4], bf1[4];
#pragma unroll
            for (int s = 0; s < 4; ++s) {
                const int soff = (((4 * s + hi) ^ swz) << 3);
                bf0[s] = *(const bf16x8*)&mi[rl * 128 + soff];
                bf1[s] = *(const bf16x8*)&mi[(16 + rl) * 128 + soff];
            }
#pragma unroll
            for (int jb = 0; jb < 8; ++jb) {
                const float4 bj4 = *(const float4*)(b1 + jb * 16 + 4 * hi);
                f32x4 c0 = { bj4.x, bj4.y, bj4.z, bj4.w };
                f32x4 c1 = c0;
#pragma unroll
                for (int s = 0; s < 4; ++s) {
                    bf16x8 afr = *(const bf16x8*)&s_w1t[(jb * 16 + rl) * 128 + (((4 * s + hi) ^ swz) << 3)];
                    c0 = MFMA16(afr, bf0[s], c0);
                    c1 = MFMA16(afr, bf1[s], c1);
                }
                const int col = jb * 16 + 4 * hi;
                const int coff = (((col >> 3) ^ swz) << 3) + (col & 7);
                int2 pk;
                pk.x = (int)pk_bf16(fmaxf(c0[0], 0.f), fmaxf(c0[1], 0.f));
                pk.y = (int)pk_bf16(fmaxf(c0[2], 0.f), fmaxf(c0[3], 0.f));
                *(int2*)&mi[rl * 128 + coff] = pk;
                pk.x = (int)pk_bf16(fmaxf(c1[0], 0.f), fmaxf(c1[1], 0.f));
                pk.y = (int)pk_bf16(fmaxf(c1[2], 0.f), fmaxf(c1[3], 0.f));
                *(int2*)&mi[(16 + rl) * 128 + coff] = pk;
            }
        }

        // ---- GEMM2 (swapped): m[e][j] = hidden @ W2 + b2 -> f32 b128 w ----
        {
            bf16x8 hf0[4], hf1[4];
#pragma unroll
            for (int s = 0; s < 4; ++s) {
                const int soff = (((4 * s + hi) ^ swz) << 3);
                hf0[s] = *(const bf16x8*)&mi[rl * 128 + soff];
                hf1[s] = *(const bf16x8*)&mi[(16 + rl) * 128 + soff];
            }
            float* s_red = (float*)mi;                 // 32x64 f32, wave region
#pragma unroll
            for (int n = 0; n < 4; ++n) {
                const float4 bj4 = *(const float4*)(b2 + n * 16 + 4 * hi);
                f32x4 c0 = { bj4.x, bj4.y, bj4.z, bj4.w };
                f32x4 c1 = c0;
#pragma unroll
                for (int s = 0; s < 4; ++s) {
                    bf16x8 afr = *(const bf16x8*)&s_w2t[(n * 16 + rl) * 128 + (((4 * s + hi) ^ swz) << 3)];
                    c0 = MFMA16(afr, hf0[s], c0);
                    c1 = MFMA16(afr, hf1[s], c1);
                }
                const int pslot = (n * 4 + hi) ^ (rl & 3);   // bank-spread slot
                *(f32x4*)&s_red[rl * 64 + pslot * 4] = c0;
                *(f32x4*)&s_red[(16 + rl) * 64 + pslot * 4] = c1;
            }
        }

        // ---- segmented reduce over the wave's 32 sorted edges ----
        {
            const float* s_red = (const float*)mi;
            const int lq = l >> 2, lo2 = l & 3;
            float acc = 0.f;
            int cur = __builtin_amdgcn_readlane(dstv, 0);
            bool first = true;
#pragma unroll
            for (int r = 0; r < 32; ++r) {
                int d = __builtin_amdgcn_readlane(dstv, r);
                if (d != cur) {
                    float* ap2 = agg + (size_t)cur * 64 + l;
                    if (first) atomicAdd(ap2, acc);
                    else       *ap2 = acc;           // interior run: exclusive
                    first = false; acc = 0.f; cur = d;
                }
                acc += s_red[r * 64 + ((lq ^ (r & 3)) << 2) + lo2];
            }
            atomicAdd(agg + (size_t)cur * 64 + l, acc);  // touches window end
        }

        chunk = nx;
    }
}

// ---------------------------------------------------------------------------
// Self update (in place): h = relu(agg + h @ self_w + self_b).
// zero_agg: zero agg after reading. last: skip all global h/hb writes and do
// fused graph pooling via block-level LDS pre-reduction (low contention).
// ---------------------------------------------------------------------------
__global__ __launch_bounds__(256)
void self_update_kernel(float* h, short* hb, float* agg,
                        const float* __restrict__ sw, const float* __restrict__ sb,
                        int zero_agg, int last,
                        const int* __restrict__ batch,
                        float* __restrict__ gsum, float* __restrict__ counts)
{
    __shared__ float s_h[16 * 64];
    __shared__ int s_b[16];
    const int t = threadIdx.x;
    const int j = t & 63, iq = t >> 6;
    const int n0 = blockIdx.x * 16;

    for (int idx = t; idx < 16 * 64; idx += 256)
        s_h[idx] = h[(size_t)n0 * 64 + idx];
    if (last && t < 16) s_b[t] = batch[n0 + t];
    __syncthreads();

    float acc[4];
    const float bj = sb[j];
#pragma unroll
    for (int q = 0; q < 4; ++q) acc[q] = bj;

#pragma unroll 4
    for (int k = 0; k < 64; ++k) {
        float wv = sw[k * 64 + j];
#pragma unroll
        for (int q = 0; q < 4; ++q)
            acc[q] += s_h[(iq + q * 4) * 64 + k] * wv;
    }

    if (!last) {
#pragma unroll
        for (int q = 0; q < 4; ++q) {
            int n = n0 + iq + q * 4;
            float v = fmaxf(acc[q] + agg[(size_t)n * 64 + j], 0.f);
            h[(size_t)n * 64 + j] = v;
            hb[(size_t)n * 64 + j] = f2bf(v);
            if (zero_agg) agg[(size_t)n * 64 + j] = 0.f;
        }
    } else {
        // compute v and park it in the (now-dead) s_h tile
        float vq[4];
#pragma unroll
        for (int q = 0; q < 4; ++q) {
            int n = n0 + iq + q * 4;
            vq[q] = fmaxf(acc[q] + agg[(size_t)n * 64 + j], 0.f);
        }
        __syncthreads();             // all s_h reads complete
#pragma unroll
        for (int q = 0; q < 4; ++q)
            s_h[(iq + q * 4) * 64 + j] = vq[q];
        __syncthreads();

        // block-level pooling: 64 threads run-length column t over 16 nodes
        if (t < 64) {
            int cur = s_b[0];
            float sum = 0.f, cnt = 0.f;
#pragma unroll
            for (int nn = 0; nn < 16; ++nn) {
                int b = s_b[nn];
                if (b != cur) {
                    atomicAdd(gsum + (size_t)cur * 64 + t, sum);
                    if (t == 0) atomicAdd(counts + cur, cnt);
                    sum = 0.f; cnt = 0.f; cur = b;
                }
                sum += s_h[nn * 64 + t];
                cnt += 1.f;
            }
            atomicAdd(gsum + (size_t)cur * 64 + t, sum);
            if (t == 0) atomicAdd(counts + cur, cnt);
        }
    }
}

// ---------------------------------------------------------------------------
// Readout
// ---------------------------------------------------------------------------
__global__ __launch_bounds__(64)
void readout_kernel(const float* __restrict__ gsum, const float* __restrict__ counts,
                    const float* __restrict__ w1, const float* __restrict__ b1,
                    const float* __restrict__ w2, const float* __restrict__ b2,
                    float* __restrict__ out)
{
    __shared__ float s_g[128];
    const int g = blockIdx.x, t = threadIdx.x;
    float sv = gsum[(size_t)g * 64 + t];
    float c = fmaxf(counts[g], 1.f);
    s_g[t] = sv;
    s_g[64 + t] = sv / c;
    __syncthreads();

    float acc = b1[t];
#pragma unroll 4
    for (int k = 0; k < 128; ++k)
        acc += s_g[k] * w1[k * 64 + t];
    acc = fmaxf(acc, 0.f);

    float p = acc * w2[t];
#pragma unroll
    for (int m = 1; m < 64; m <<= 1)
        p += __shfl_xor(p, m, 64);
    if (t == 0) out[g] = p + b2[0];
}

// ---------------------------------------------------------------------------
extern "C" void kernel_launch(void* const* d_in, const int* in_sizes, int n_in,
                              void* d_out, int out_size, void* d_ws, size_t ws_size,
                              hipStream_t stream)
{
    const float* x      = (const float*)d_in[0];
    const int*   eidx   = (const int*)d_in[1];
    const float* eattr  = (const float*)d_in[2];
    const int*   batch  = (const int*)d_in[3];
    const float* node_w = (const float*)d_in[4];
    const float* node_b = (const float*)d_in[5];
    const float* edge_w = (const float*)d_in[6];
    const float* edge_b = (const float*)d_in[7];
    const float* msg_w1 = (const float*)d_in[8];
    const float* msg_b1 = (const float*)d_in[9];
    const float* msg_w2 = (const float*)d_in[10];
    const float* msg_b2 = (const float*)d_in[11];
    const float* self_w = (const float*)d_in[12];
    const float* self_b = (const float*)d_in[13];
    const float* ro_w1  = (const float*)d_in[14];
    const float* ro_b1  = (const float*)d_in[15];
    const float* ro_w2  = (const float*)d_in[16];
    const float* ro_b2  = (const float*)d_in[17];
    float* out = (float*)d_out;

    char* wsp = (char*)d_ws;
    float* h      = (float*)wsp;                         wsp += (size_t)N_NODES * 64 * 4;
    float* agg    = (float*)wsp;                         wsp += (size_t)N_NODES * 64 * 4;
    short* hb     = (short*)wsp;                         wsp += (size_t)N_NODES * 64 * 2;
    int*   src_p  = (int*)wsp;                           wsp += (size_t)N_EDGES * 4;
    int*   dst_p  = (int*)wsp;                           wsp += (size_t)N_EDGES * 4;
    short* ea_p   = (short*)wsp;                         wsp += (size_t)N_EDGES * 16 * 2;
    float* gsum   = (float*)wsp;                         wsp += (size_t)N_GRAPH * 64 * 4;
    float* counts = (float*)wsp;                         wsp += (size_t)N_GRAPH * 4;
    int*   cnt    = (int*)wsp;                           wsp += (size_t)CNTPAD * 4;
    int*   pos    = (int*)wsp;                           wsp += (size_t)CNTPAD * 4;
    int*   bsums  = (int*)wsp;                           wsp += (size_t)(NCHUNK + 32) * 4;

    const int* srcp = eidx;
    const int* dstp = eidx + N_EDGES;

    // cnt/pos must be zero before the fused histogram in node_embed
    hipMemsetAsync(cnt, 0, (size_t)(2 * CNTPAD + 128) * sizeof(int), stream);

    // node embedding + agg zero + gsum/counts zero + dst histogram
    node_embed_kernel<<<N_NODES / 16, 256, 0, stream>>>(
        x, node_w, node_b, h, hb, agg, dstp, cnt, gsum);

    // ---- one-time dst-sort of edges ----
    scan_chunk_sums<<<NCHUNK, 256, 0, stream>>>(cnt, bsums);
    scan_bsums<<<1, 64, 0, stream>>>(bsums);
    scan_apply<<<NCHUNK, 1024, 0, stream>>>(cnt, bsums);
    scatter_kernel<<<(N_EDGES + 255) / 256, 256, 0, stream>>>(
        srcp, dstp, eattr, cnt, pos, src_p, dst_p, ea_p);

    for (int l = 0; l < NLAYER; ++l) {
        edge_mlp_mfma<<<256, 768, 0, stream>>>(
            hb, src_p, dst_p, ea_p, edge_w, edge_b,
            msg_w1 + (size_t)l * 128 * 128, msg_b1 + (size_t)l * 128,
            msg_w2 + (size_t)l * 128 * 64,  msg_b2 + (size_t)l * 64,
            agg);
        self_update_kernel<<<N_NODES / 16, 256, 0, stream>>>(
            h, hb, agg, self_w + (size_t)l * 64 * 64, self_b + (size_t)l * 64,
            (l < NLAYER - 1) ? 1 : 0, (l == NLAYER - 1) ? 1 : 0,
            batch, gsum, counts);
    }

    readout_kernel<<<N_GRAPH, 64, 0, stream>>>(gsum, counts, ro_w1, ro_b1, ro_w2, ro_b2, out);
}